// Round 1
// baseline (173.074 us; speedup 1.0000x reference)
//
#include <hip/hip_runtime.h>

#define NN   100000
#define KNB  32
#define DIN  256
#define DOUT 128

typedef __attribute__((ext_vector_type(8))) short short8;   // 8 x bf16 (4 VGPRs)
typedef __attribute__((ext_vector_type(4))) float f32x4;    // 4 x f32

__device__ __forceinline__ unsigned short f2bf(float f) {
    unsigned u = __float_as_uint(f);
    u += 0x7fffu + ((u >> 16) & 1u);          // round-to-nearest-even
    return (unsigned short)(u >> 16);
}

// ---------------------------------------------------------------------------
// Kernel 0: W [DIN][DOUT] f32  ->  Wt [DOUT][DIN] bf16 (transposed + converted)
// ---------------------------------------------------------------------------
__global__ void wt_conv(const float* __restrict__ W, unsigned short* __restrict__ Wt) {
    int t = blockIdx.x * 256 + threadIdx.x;   // 0 .. 32767
    int d = t >> 8;                           // dout
    int k = t & 255;                          // din
    Wt[t] = f2bf(W[(size_t)k * DOUT + d]);
}

// ---------------------------------------------------------------------------
// Kernel 1: h = relu(feats @ W + b), stored bf16.
// Operand-swapped MFMA: A = Wt (M-dim = DOUT), B = feats^T (N-dim = nodes).
// Wave handles 32 nodes x 128 douts. No LDS: Wt streams from L2 (64 KB total),
// feats f32 loads are converted to bf16 in-register.
// ---------------------------------------------------------------------------
__global__ __launch_bounds__(256) void gemm_relu(
        const float* __restrict__ feats, const unsigned short* __restrict__ Wt,
        const float* __restrict__ bias, unsigned short* __restrict__ h) {
    const int lane = threadIdx.x & 63;
    const int wid  = threadIdx.x >> 6;
    const int l16  = lane & 15;
    const int lq   = lane >> 4;
    const int nodeBase = blockIdx.x * 128 + wid * 32;

    f32x4 acc[8][2];
    #pragma unroll
    for (int mf = 0; mf < 8; ++mf) { acc[mf][0] = (f32x4)0.f; acc[mf][1] = (f32x4)0.f; }

    int n0 = nodeBase + l16;
    int n1 = nodeBase + 16 + l16;
    int n0c = n0 < NN ? n0 : NN - 1;          // clamp loads; stores are predicated
    int n1c = n1 < NN ? n1 : NN - 1;
    const float* f0p = feats + (size_t)n0c * DIN + lq * 8;
    const float* f1p = feats + (size_t)n1c * DIN + lq * 8;
    const unsigned short* wp = Wt + l16 * DIN + lq * 8;

    #pragma unroll
    for (int ks = 0; ks < 8; ++ks) {
        short8 bfrag[2];
        {
            f32x4 a0 = *(const f32x4*)(f0p + ks * 32);
            f32x4 a1 = *(const f32x4*)(f0p + ks * 32 + 4);
            short8 t;
            t[0]=f2bf(a0[0]); t[1]=f2bf(a0[1]); t[2]=f2bf(a0[2]); t[3]=f2bf(a0[3]);
            t[4]=f2bf(a1[0]); t[5]=f2bf(a1[1]); t[6]=f2bf(a1[2]); t[7]=f2bf(a1[3]);
            bfrag[0] = t;
        }
        {
            f32x4 a0 = *(const f32x4*)(f1p + ks * 32);
            f32x4 a1 = *(const f32x4*)(f1p + ks * 32 + 4);
            short8 t;
            t[0]=f2bf(a0[0]); t[1]=f2bf(a0[1]); t[2]=f2bf(a0[2]); t[3]=f2bf(a0[3]);
            t[4]=f2bf(a1[0]); t[5]=f2bf(a1[1]); t[6]=f2bf(a1[2]); t[7]=f2bf(a1[3]);
            bfrag[1] = t;
        }
        #pragma unroll
        for (int mf = 0; mf < 8; ++mf) {
            short8 a = *(const short8*)(wp + mf * 16 * DIN + ks * 32);
            acc[mf][0] = __builtin_amdgcn_mfma_f32_16x16x32_bf16(a, bfrag[0], acc[mf][0], 0, 0, 0);
            acc[mf][1] = __builtin_amdgcn_mfma_f32_16x16x32_bf16(a, bfrag[1], acc[mf][1], 0, 0, 0);
        }
    }

    // Epilogue: bias + relu + pack 4 bf16 -> 8 B store.
    // D layout: col (node) = lane&15, row (dout) = (lane>>4)*4 + reg  [m89-verified]
    #pragma unroll
    for (int mf = 0; mf < 8; ++mf) {
        int dbase = mf * 16 + lq * 4;
        f32x4 bv = *(const f32x4*)(bias + dbase);
        #pragma unroll
        for (int nf = 0; nf < 2; ++nf) {
            int node = nodeBase + nf * 16 + l16;
            if (node < NN) {
                f32x4 v = acc[mf][nf];
                float v0 = fmaxf(v[0] + bv[0], 0.f);
                float v1 = fmaxf(v[1] + bv[1], 0.f);
                float v2 = fmaxf(v[2] + bv[2], 0.f);
                float v3 = fmaxf(v[3] + bv[3], 0.f);
                unsigned u0 = (unsigned)f2bf(v0) | ((unsigned)f2bf(v1) << 16);
                unsigned u1 = (unsigned)f2bf(v2) | ((unsigned)f2bf(v3) << 16);
                uint2 st = make_uint2(u0, u1);
                *(uint2*)(h + (size_t)node * DOUT + dbase) = st;
            }
        }
    }
}

// ---------------------------------------------------------------------------
// Kernel 2: out[n] = mean_k h_bf16[edge[n][k]]   (half-wave of 32 lanes / node)
// ---------------------------------------------------------------------------
__global__ __launch_bounds__(256) void gather_mean(
        const int* __restrict__ edge, const unsigned short* __restrict__ h,
        float* __restrict__ out) {
    const int l   = threadIdx.x & 31;
    const int hw  = (blockIdx.x * 256 + threadIdx.x) >> 5;
    const int nHW = gridDim.x * 8;
    for (int n = hw; n < NN; n += nHW) {
        int myIdx = edge[n * KNB + l];        // coalesced 128 B per half-wave
        float s0 = 0.f, s1 = 0.f, s2 = 0.f, s3 = 0.f;
        #pragma unroll
        for (int k = 0; k < KNB; ++k) {
            int e = __shfl(myIdx, k, 32);     // broadcast within half-wave
            uint2 v = *(const uint2*)(h + (size_t)e * DOUT + l * 4);
            s0 += __uint_as_float(v.x << 16);
            s1 += __uint_as_float(v.x & 0xffff0000u);
            s2 += __uint_as_float(v.y << 16);
            s3 += __uint_as_float(v.y & 0xffff0000u);
        }
        f32x4 o = { s0 * (1.f/KNB), s1 * (1.f/KNB), s2 * (1.f/KNB), s3 * (1.f/KNB) };
        *(f32x4*)(out + (size_t)n * DOUT + l * 4) = o;
    }
}

// ---------------------------------------------------------------------------
extern "C" void kernel_launch(void* const* d_in, const int* in_sizes, int n_in,
                              void* d_out, int out_size, void* d_ws, size_t ws_size,
                              hipStream_t stream) {
    const float* feats = (const float*)d_in[0];   // [100000,256] f32
    const int*   edge  = (const int*)d_in[1];     // [100000,32] i32
    const float* W     = (const float*)d_in[2];   // [256,128] f32
    const float* b     = (const float*)d_in[3];   // [128] f32
    float* out = (float*)d_out;                   // [100000,128] f32

    unsigned short* Wt = (unsigned short*)d_ws;                    // 64 KB
    unsigned short* h  = (unsigned short*)((char*)d_ws + 65536);   // 25.6 MB

    wt_conv<<<128, 256, 0, stream>>>(W, Wt);
    gemm_relu<<<(NN + 127) / 128, 256, 0, stream>>>(feats, Wt, b, h);
    gather_mean<<<2048, 256, 0, stream>>>(edge, h, out);
}